// Round 2
// baseline (153.821 us; speedup 1.0000x reference)
//
#include <hip/hip_runtime.h>

#define TPB 1024
#define NW (TPB / 64)
#define NCOLS 16384
#define F4PT 4                  // 4 float4 per thread
#define NELEM 16                // 16 elements per thread
#define BINS1 8192              // pass1: key >> 18 (13 bits: sign+8exp+4mant)
#define SH1 18
#define CAP 1024                // candidate list capacity (expected E ~160)

__device__ __forceinline__ unsigned keyOf(float f) {
    return __float_as_uint(f) & 0x7fffffffu;
}

// Block-wide descending (suffix) select over hist[NBINS]: finds bin b s.t.
// sum(hist[b..NBINS-1]) first reaches >= Krem scanning from the top.
// bc[0]=cut bin, bc[1]=quota within bin, bc[2]=bin population.
// Caller must have synced hist; ends with __syncthreads().
template <int NBINS>
__device__ void suffix_select(const unsigned* hist, unsigned Krem,
                              unsigned* wsums, unsigned* bc) {
    const int t = threadIdx.x;
    const int lane = t & 63;
    const int wave = t >> 6;
    constexpr int CH = (NBINS + TPB - 1) / TPB;
    const int base = t * CH;
    unsigned c = 0;
#pragma unroll
    for (int i = 0; i < CH; ++i)
        if (base + i < NBINS) c += hist[base + i];
    // in-wave inclusive suffix scan
    unsigned s = c;
#pragma unroll
    for (int off = 1; off < 64; off <<= 1) {
        unsigned o = __shfl_down(s, off);
        if (lane + off < 64) s += o;
    }
    if (lane == 0) wsums[wave] = s;
    __syncthreads();
    if (wave == 0) {
        unsigned ws = (lane < NW) ? wsums[lane] : 0u;
        unsigned ss = ws;
#pragma unroll
        for (int off = 1; off < 64; off <<= 1) {
            unsigned o = __shfl_down(ss, off);
            if (lane + off < 64) ss += o;
        }
        if (lane < NW) wsums[lane] = ss;
    }
    __syncthreads();
    unsigned gts = ((wave + 1 < NW) ? wsums[wave + 1] : 0u) + (s - c);
    if (gts < Krem && gts + c >= Krem) {   // exactly one thread brackets the cut
        unsigned cum = gts;
        for (int i = CH - 1; i >= 0; --i) {
            unsigned h = hist[base + i];   // re-read (cheap) instead of caching
            cum += h;
            if (cum >= Krem) {
                bc[0] = (unsigned)(base + i);
                bc[1] = Krem - (cum - h);
                bc[2] = h;
                break;
            }
        }
    }
    __syncthreads();
}

__global__ __launch_bounds__(TPB, 8) void topk_mask_kernel(
        const float* __restrict__ x, const int* __restrict__ kp,
        float* __restrict__ out) {
    __shared__ unsigned hist[BINS1];          // 32 KB
    __shared__ unsigned candKey[CAP];         // 4 KB
    __shared__ unsigned candIdx[CAP];         // 4 KB
    __shared__ unsigned bitmap[NCOLS / 32];   // 2 KB keep-bits for cut-bin elems
    __shared__ unsigned wsums[NW];
    __shared__ unsigned bc[3];
    __shared__ unsigned cnt;

    const int t = threadIdx.x;
    const unsigned K = (unsigned)(*kp);
    const size_t row = blockIdx.x;
    const float4* xr = reinterpret_cast<const float4*>(x) + row * (NCOLS / 4);
    float4* orow = reinterpret_cast<float4*>(out) + row * (NCOLS / 4);

    // Load entire row into registers once; held through all phases.
    float vals[NELEM];
#pragma unroll
    for (int i = 0; i < F4PT; ++i) {
        float4 tmp = xr[t + i * TPB];
        vals[4 * i + 0] = tmp.x;
        vals[4 * i + 1] = tmp.y;
        vals[4 * i + 2] = tmp.z;
        vals[4 * i + 3] = tmp.w;
    }

    // zero hist + bitmap + cnt
#pragma unroll
    for (int i = 0; i < BINS1 / TPB; ++i) hist[t + i * TPB] = 0u;
    if (t < NCOLS / 32) bitmap[t] = 0u;
    if (t == 0) cnt = 0u;
    __syncthreads();

    // ---------- single 13-bit histogram pass ----------
#pragma unroll
    for (int e = 0; e < NELEM; ++e)
        atomicAdd(&hist[keyOf(vals[e]) >> SH1], 1u);
    __syncthreads();
    suffix_select<BINS1>(hist, K, wsums, bc);
    const unsigned cut1 = bc[0];
    const unsigned r1 = bc[1];   // quota within cut bin
    const unsigned E = bc[2];    // cut bin population

    unsigned thrKey = 0;         // fallback exact threshold key
    const bool fastp = (E <= CAP);

    if (fastp) {
        // compact cut-bin candidates
#pragma unroll
        for (int e = 0; e < NELEM; ++e) {
            unsigned key = keyOf(vals[e]);
            if ((key >> SH1) == cut1) {
                unsigned idx = 4u * (unsigned)(t + (e >> 2) * TPB) + (e & 3);
                unsigned p = atomicAdd(&cnt, 1u);
                candKey[p] = key;
                candIdx[p] = idx;
            }
        }
        __syncthreads();
        // exact rank (key desc, idx asc = jax top_k tie order); keep r1 best
        for (unsigned p = t; p < E; p += TPB) {
            unsigned key = candKey[p], idx = candIdx[p], rank = 0;
            for (unsigned q = 0; q < E; ++q) {
                unsigned ck = candKey[q];
                rank += (ck > key) || (ck == key && candIdx[q] < idx);
            }
            if (rank < r1) atomicOr(&bitmap[idx >> 5], 1u << (idx & 31));
        }
        __syncthreads();
    } else {
        // ---------- generic fallback: refine 18 low bits in two passes ----------
        if (t < 1024) hist[t] = 0u;
        __syncthreads();
#pragma unroll
        for (int e = 0; e < NELEM; ++e) {
            unsigned key = keyOf(vals[e]);
            if ((key >> SH1) == cut1) atomicAdd(&hist[(key >> 8) & 1023u], 1u);
        }
        __syncthreads();
        suffix_select<1024>(hist, r1, wsums, bc);
        const unsigned pfx = (cut1 << 10) | bc[0];   // key>>8 prefix
        const unsigned r2 = bc[1];
        if (t < 256) hist[t] = 0u;
        __syncthreads();
#pragma unroll
        for (int e = 0; e < NELEM; ++e) {
            unsigned key = keyOf(vals[e]);
            if ((key >> 8) == pfx) atomicAdd(&hist[key & 255u], 1u);
        }
        __syncthreads();
        suffix_select<256>(hist, r2, wsums, bc);
        thrKey = (pfx << 8) | bc[0];
        const unsigned rQ = bc[1];   // quota among exact equals
        // rank exact-equal keys by index (lowest idx kept first)
        if (t == 0) cnt = 0u;
        __syncthreads();
#pragma unroll
        for (int e = 0; e < NELEM; ++e) {
            if (keyOf(vals[e]) == thrKey) {
                unsigned idx = 4u * (unsigned)(t + (e >> 2) * TPB) + (e & 3);
                unsigned p = atomicAdd(&cnt, 1u);
                if (p < CAP) candIdx[p] = idx;
            }
        }
        __syncthreads();
        unsigned m = cnt < CAP ? cnt : CAP;
        for (unsigned p = t; p < m; p += TPB) {
            unsigned idx = candIdx[p], rank = 0;
            for (unsigned q = 0; q < m; ++q) rank += candIdx[q] < idx;
            if (rank < rQ) atomicOr(&bitmap[idx >> 5], 1u << (idx & 31));
        }
        __syncthreads();
    }

    // ---------- write ----------
#pragma unroll
    for (int i = 0; i < F4PT; ++i) {
        float4 o;
#pragma unroll
        for (int j = 0; j < 4; ++j) {
            float v = vals[4 * i + j];
            unsigned key = keyOf(v);
            unsigned idx = 4u * (unsigned)(t + i * TPB) + j;
            bool keep;
            if (fastp) {
                unsigned b = key >> SH1;
                keep = (b > cut1) ||
                       (b == cut1 && ((bitmap[idx >> 5] >> (idx & 31)) & 1u));
            } else {
                keep = (key > thrKey) ||
                       (key == thrKey && ((bitmap[idx >> 5] >> (idx & 31)) & 1u));
            }
            (&o.x)[j] = keep ? v : 0.0f;
        }
        orow[t + i * TPB] = o;
    }
}

extern "C" void kernel_launch(void* const* d_in, const int* in_sizes, int n_in,
                              void* d_out, int out_size, void* d_ws, size_t ws_size,
                              hipStream_t stream) {
    const float* x = (const float*)d_in[0];
    const int* kp = (const int*)d_in[1];
    float* out = (float*)d_out;
    const int rows = in_sizes[0] / NCOLS;   // 4096
    topk_mask_kernel<<<rows, TPB, 0, stream>>>(x, kp, out);
}

// Round 3
// 150.534 us; speedup vs baseline: 1.0218x; 1.0218x over previous
//
#include <hip/hip_runtime.h>

#define TPB 512
#define NW (TPB / 64)
#define NCOLS 16384
#define F4PT 8                   // 8 float4 per thread
#define EPT 32                   // 32 elements per thread
#define BINS1 8192               // pass1: key >> 18 (13 bits)
#define SH1 18
#define HSZ (BINS1 + BINS1 / 16) // padded: bin b stored at b + b/16
#define CAP 512                  // candidate capacity (expected E ~160)

__device__ __forceinline__ unsigned keyOf(float f) {
    return __float_as_uint(f) & 0x7fffffffu;
}
__device__ __forceinline__ unsigned padded(unsigned b) { return b + (b >> 4); }

// Block-wide descending (suffix) select over hist[NBINS]: finds bin b s.t.
// sum(hist[b..NBINS-1]) first reaches >= Krem scanning from the top.
// bc[0]=cut bin, bc[1]=quota within bin, bc[2]=bin population.
// Caller synced hist; ends with __syncthreads().
template <int NBINS, bool PAD>
__device__ void suffix_select(const unsigned* hist, unsigned Krem,
                              unsigned* wsums, unsigned* bc) {
    const int t = threadIdx.x;
    const int lane = t & 63;
    const int wave = t >> 6;
    constexpr int CH = (NBINS + TPB - 1) / TPB;
    const int base = t * CH;
    unsigned c = 0;
#pragma unroll
    for (int i = 0; i < CH; ++i) {
        int b = base + i;
        if (b < NBINS) c += hist[PAD ? padded((unsigned)b) : (unsigned)b];
    }
    unsigned s = c;  // in-wave inclusive suffix scan
#pragma unroll
    for (int off = 1; off < 64; off <<= 1) {
        unsigned o = __shfl_down(s, off);
        if (lane + off < 64) s += o;
    }
    if (lane == 0) wsums[wave] = s;
    __syncthreads();
    if (wave == 0) {
        unsigned ws = (lane < NW) ? wsums[lane] : 0u;
        unsigned ss = ws;
#pragma unroll
        for (int off = 1; off < 64; off <<= 1) {
            unsigned o = __shfl_down(ss, off);
            if (lane + off < 64) ss += o;
        }
        if (lane < NW) wsums[lane] = ss;
    }
    __syncthreads();
    unsigned gts = ((wave + 1 < NW) ? wsums[wave + 1] : 0u) + (s - c);
    if (gts < Krem && gts + c >= Krem) {  // exactly one thread brackets the cut
        unsigned cum = gts;
        for (int i = CH - 1; i >= 0; --i) {
            int b = base + i;
            if (b >= NBINS) continue;
            unsigned h = hist[PAD ? padded((unsigned)b) : (unsigned)b];
            cum += h;
            if (cum >= Krem) {
                bc[0] = (unsigned)b;
                bc[1] = Krem - (cum - h);
                bc[2] = h;
                break;
            }
        }
    }
    __syncthreads();
}

__global__ __launch_bounds__(TPB, 6) void topk_mask_kernel(
        const float* __restrict__ x, const int* __restrict__ kp,
        float* __restrict__ out) {
    __shared__ unsigned hist[HSZ];            // 34 KB (padded)
    __shared__ unsigned cand[CAP];            // 2 KB packed (keyLow18<<14 | ~idx)
    __shared__ unsigned bitmap[NCOLS / 32];   // 2 KB keep-bits for cut-bin elems
    __shared__ unsigned wsums[NW];
    __shared__ unsigned bc[3];
    __shared__ unsigned cnt;

    const int t = threadIdx.x;
    const unsigned K = (unsigned)(*kp);
    const size_t row = blockIdx.x;
    const float4* xr = reinterpret_cast<const float4*>(x) + row * (NCOLS / 4);
    float4* orow = reinterpret_cast<float4*>(out) + row * (NCOLS / 4);

    // Load entire row into registers once.
    float vals[EPT];
#pragma unroll
    for (int i = 0; i < F4PT; ++i) {
        float4 tmp = xr[t + i * TPB];
        vals[4 * i + 0] = tmp.x;
        vals[4 * i + 1] = tmp.y;
        vals[4 * i + 2] = tmp.z;
        vals[4 * i + 3] = tmp.w;
    }
    // Pin in registers: opaque asm output can't be rematerialized by re-loading.
#pragma unroll
    for (int e = 0; e < EPT; ++e) asm volatile("" : "+v"(vals[e]));

    // zero hist + bitmap + cnt
#pragma unroll
    for (int i = 0; i < (HSZ + TPB - 1) / TPB; ++i)
        if (t + i * TPB < HSZ) hist[t + i * TPB] = 0u;
    if (t < NCOLS / 32) bitmap[t] = 0u;
    if (t == 0) cnt = 0u;
    __syncthreads();

    // ---------- single 13-bit histogram pass ----------
#pragma unroll
    for (int e = 0; e < EPT; ++e)
        atomicAdd(&hist[padded(keyOf(vals[e]) >> SH1)], 1u);
    __syncthreads();
    suffix_select<BINS1, true>(hist, K, wsums, bc);
    const unsigned cut1 = bc[0];
    const unsigned r1 = bc[1];   // quota within cut bin
    const unsigned E = bc[2];    // cut bin population

    unsigned thrKey = 0;
    const bool fastp = (E <= CAP);

    if (fastp) {
        // compact cut-bin candidates, packed so (key desc, idx asc) == word desc
#pragma unroll
        for (int e = 0; e < EPT; ++e) {
            unsigned key = keyOf(vals[e]);
            if ((key >> SH1) == cut1) {
                unsigned idx = 4u * (unsigned)(t + (e >> 2) * TPB) + (e & 3);
                unsigned p = atomicAdd(&cnt, 1u);
                cand[p] = ((key & 0x3FFFFu) << 14) | (idx ^ 0x3FFFu);
            }
        }
        __syncthreads();
        for (unsigned p = t; p < E; p += TPB) {
            unsigned w = cand[p], rank = 0;
            for (unsigned q = 0; q < E; ++q) rank += (cand[q] > w);
            if (rank < r1) {
                unsigned idx = (w & 0x3FFFu) ^ 0x3FFFu;
                atomicOr(&bitmap[idx >> 5], 1u << (idx & 31));
            }
        }
        __syncthreads();
    } else {
        // ---------- generic fallback: refine 18 low bits (10 + 8) ----------
        if (t < 1024) hist[t] = 0u;
        __syncthreads();
#pragma unroll
        for (int e = 0; e < EPT; ++e) {
            unsigned key = keyOf(vals[e]);
            if ((key >> SH1) == cut1) atomicAdd(&hist[(key >> 8) & 1023u], 1u);
        }
        __syncthreads();
        suffix_select<1024, false>(hist, r1, wsums, bc);
        const unsigned pfx = (cut1 << 10) | bc[0];
        const unsigned r2 = bc[1];
        if (t < 256) hist[t] = 0u;
        __syncthreads();
#pragma unroll
        for (int e = 0; e < EPT; ++e) {
            unsigned key = keyOf(vals[e]);
            if ((key >> 8) == pfx) atomicAdd(&hist[key & 255u], 1u);
        }
        __syncthreads();
        suffix_select<256, false>(hist, r2, wsums, bc);
        thrKey = (pfx << 8) | bc[0];
        const unsigned rQ = bc[1];
        if (t == 0) cnt = 0u;
        __syncthreads();
#pragma unroll
        for (int e = 0; e < EPT; ++e) {
            if (keyOf(vals[e]) == thrKey) {
                unsigned idx = 4u * (unsigned)(t + (e >> 2) * TPB) + (e & 3);
                unsigned p = atomicAdd(&cnt, 1u);
                if (p < CAP) cand[p] = idx;
            }
        }
        __syncthreads();
        unsigned m = cnt < CAP ? cnt : CAP;
        for (unsigned p = t; p < m; p += TPB) {
            unsigned idx = cand[p], rank = 0;
            for (unsigned q = 0; q < m; ++q) rank += cand[q] < idx;
            if (rank < rQ) atomicOr(&bitmap[idx >> 5], 1u << (idx & 31));
        }
        __syncthreads();
    }

    // ---------- write ----------
#pragma unroll
    for (int i = 0; i < F4PT; ++i) {
        float4 o;
#pragma unroll
        for (int j = 0; j < 4; ++j) {
            float v = vals[4 * i + j];
            unsigned key = keyOf(v);
            unsigned idx = 4u * (unsigned)(t + i * TPB) + j;
            bool keep;
            if (fastp) {
                unsigned b = key >> SH1;
                keep = (b > cut1) ||
                       (b == cut1 && ((bitmap[idx >> 5] >> (idx & 31)) & 1u));
            } else {
                keep = (key > thrKey) ||
                       (key == thrKey && ((bitmap[idx >> 5] >> (idx & 31)) & 1u));
            }
            (&o.x)[j] = keep ? v : 0.0f;
        }
        orow[t + i * TPB] = o;
    }
}

extern "C" void kernel_launch(void* const* d_in, const int* in_sizes, int n_in,
                              void* d_out, int out_size, void* d_ws, size_t ws_size,
                              hipStream_t stream) {
    const float* x = (const float*)d_in[0];
    const int* kp = (const int*)d_in[1];
    float* out = (float*)d_out;
    const int rows = in_sizes[0] / NCOLS;   // 4096
    topk_mask_kernel<<<rows, TPB, 0, stream>>>(x, kp, out);
}